// Round 2
// baseline (438.813 us; speedup 1.0000x reference)
//
#include <hip/hip_runtime.h>
#include <hip/hip_bf16.h>
#include <math.h>

typedef __bf16 bf16_t;
typedef __bf16 bf16x8 __attribute__((ext_vector_type(8)));
typedef float  f32x4  __attribute__((ext_vector_type(4)));

#define WPB 4    // waves per block

// MFMA 16x16x32 layouts (m89/m120-verified):
//   A: lane(m = lane&15, q = lane>>4) holds A[m][8q+j], j=0..7
//   B: lane(n = lane&15, q)           holds B[8q+j][n]
//   C: lane(n = lane&15, q) reg r     holds C[4q+r][n]
//
// r4 restructure: operand-SWAPPED MFMA — compute y^T = W^T x^T.
// A/B frag layout symmetry means the weight gathers below are BIT-IDENTICAL
// to the old B-frags; they are simply passed as the A operand now.
// Output C-layout becomes row-per-lane: lane(n,q) reg r = y[n][16t+4q+r].
//  -> layer transitions are a 4-lane q-group exchange (ds_bpermute), zero LDS
//  -> rgb store is a direct coalesced dwordx4 per lane, no LDS repack
//  -> bias rides in as the MFMA C operand (3-address), no acc-init movs
//
// Transpose algebra (re-verified r5): dest lane(n_d,q_d) dword d, chunk cc
// needs channel 32cc+8q_d+2d+p  ->  src tile t=2cc+(q_d>>1),
// src q_s=2(q_d&1)+(d>>1), src reg-pair d&1, src lane n_d+16q_s.
//
// r5 delta: non-temporal hints on the feat stream (read-once) and the
// rgb/sigma streams (write-once) — keep L2 for weights, avoid wr-allocate.
//
// r3 lesson (kept): pin() makes weight/bias fragments opaque so LLVM cannot
// rematerialize the invariant global loads inside the loop.

__device__ __forceinline__ void pin8(bf16x8& x) {
    f32x4 t = __builtin_bit_cast(f32x4, x);
    asm volatile("" : "+v"(t));
    x = __builtin_bit_cast(bf16x8, t);
}
__device__ __forceinline__ void pin4(f32x4& x) { asm volatile("" : "+v"(x)); }

__device__ __forceinline__ bf16x8 cvt8(f32x4 lo, f32x4 hi) {
    bf16x8 r;
    #pragma unroll
    for (int j = 0; j < 4; ++j) { r[j] = (bf16_t)lo[j]; r[4 + j] = (bf16_t)hi[j]; }
    return r;
}

// ReLU + bf16 pair-pack + cross-lane q-group transpose.
//  in : acc[t], lane(n,q) reg r = x[n][16t + 4q + r]   (pre-ReLU, fp32)
//  out: o[c],   lane(n,q) dword d = bf16pair x[n][32c + 8q + 2d .. +1]
//       == the B-frag (K-chunk c) for the next swapped-operand MFMA.
__device__ __forceinline__ void relu_xpose(const f32x4 acc[4], bf16x8 o[2],
                                           int addrA, int addrB, bool hiq) {
    int pk[4][2];
    #pragma unroll
    for (int t = 0; t < 4; ++t)
        #pragma unroll
        for (int p = 0; p < 2; ++p) {
            union { struct { bf16_t l, h; } s; int i; } u;
            u.s.l = (bf16_t)fmaxf(acc[t][2*p    ], 0.0f);   // adjacent pair ->
            u.s.h = (bf16_t)fmaxf(acc[t][2*p + 1], 0.0f);   // v_cvt_pk_bf16_f32
            pk[t][p] = u.i;
        }
    #pragma unroll
    for (int c = 0; c < 2; ++c) {
        int lo0 = __builtin_amdgcn_ds_bpermute(addrA, pk[2*c    ][0]);
        int lo1 = __builtin_amdgcn_ds_bpermute(addrA, pk[2*c    ][1]);
        int lo2 = __builtin_amdgcn_ds_bpermute(addrB, pk[2*c    ][0]);
        int lo3 = __builtin_amdgcn_ds_bpermute(addrB, pk[2*c    ][1]);
        int hi0 = __builtin_amdgcn_ds_bpermute(addrA, pk[2*c + 1][0]);
        int hi1 = __builtin_amdgcn_ds_bpermute(addrA, pk[2*c + 1][1]);
        int hi2 = __builtin_amdgcn_ds_bpermute(addrB, pk[2*c + 1][0]);
        int hi3 = __builtin_amdgcn_ds_bpermute(addrB, pk[2*c + 1][1]);
        union { int i[4]; bf16x8 v; } f;
        f.i[0] = hiq ? hi0 : lo0;
        f.i[1] = hiq ? hi1 : lo1;
        f.i[2] = hiq ? hi2 : lo2;
        f.i[3] = hiq ? hi3 : lo3;
        o[c] = f.v;
    }
}

__global__ __launch_bounds__(256, 3)   // zero LDS, ~150 live VGPR -> 12 waves/CU
void ngp_mlp_kernel(const float* __restrict__ feat,
                    const float* __restrict__ W0,
                    const float* __restrict__ b0,
                    const float* __restrict__ W1,
                    const float* __restrict__ b1,
                    const float* __restrict__ Ws,
                    const float* __restrict__ bs,
                    const float* __restrict__ Wr,
                    const float* __restrict__ br,
                    float* __restrict__ out_sigma,
                    float* __restrict__ out_rgb,
                    int num_tiles, int wave_stride)
{
    const int tid  = threadIdx.x;
    const int wid  = tid >> 6;
    const int lane = tid & 63;
    const int n    = lane & 15;
    const int q    = lane >> 4;
    const bool hiq = (lane >= 32);                 // q >= 2

    // bpermute source-lane addresses (bytes): lane n + 16*q_s
    const int addrA = ((n + 32 * (q & 1)) << 2);   // q_s = 2(q&1)
    const int addrB = addrA + 64;                  // q_s = 2(q&1)+1

    // ---------- one-time weight fragment construction (L2/L3-resident) ----------
    bf16x8 w0f[4];                       // W0 [32 x 64]: A'-frag tile t (= old B-frag)
    #pragma unroll
    for (int t = 0; t < 4; ++t)
        #pragma unroll
        for (int j = 0; j < 8; ++j)
            w0f[t][j] = (bf16_t)W0[(8*q + j)*64 + 16*t + n];

    bf16x8 w1f[4][2];                    // W1 [64 x 64]: tile t, K-chunk c
    #pragma unroll
    for (int t = 0; t < 4; ++t)
        #pragma unroll
        for (int c = 0; c < 2; ++c)
            #pragma unroll
            for (int j = 0; j < 8; ++j)
                w1f[t][c][j] = (bf16_t)W1[(32*c + 8*q + j)*64 + 16*t + n];

    bf16x8 whf[2][2];                    // heads: tile0 = Wr^T rows, tile1 row0 = Ws^T
    #pragma unroll
    for (int c = 0; c < 2; ++c)
        #pragma unroll
        for (int j = 0; j < 8; ++j) {
            whf[0][c][j] = (bf16_t)Wr[(32*c + 8*q + j)*16 + n];
            whf[1][c][j] = (n == 0) ? (bf16_t)Ws[32*c + 8*q + j] : (bf16_t)0.0f;
        }

    // per-output-channel biases: channel = 16t + 4q + r  -> f32x4 per tile
    f32x4 b0q[4], b1q[4];
    #pragma unroll
    for (int t = 0; t < 4; ++t) {
        b0q[t] = *(const f32x4*)(b0 + 16*t + 4*q);
        b1q[t] = *(const f32x4*)(b1 + 16*t + 4*q);
    }
    f32x4 brq = *(const f32x4*)(br + 4*q);
    f32x4 sIn = (f32x4){ (q == 0) ? (bs[0] - 1.0f) : 0.0f, 0.0f, 0.0f, 0.0f };

    // ---- pin everything: kill invariant-load rematerialization ----
    #pragma unroll
    for (int t = 0; t < 4; ++t) pin8(w0f[t]);
    #pragma unroll
    for (int t = 0; t < 4; ++t)
        #pragma unroll
        for (int c = 0; c < 2; ++c) pin8(w1f[t][c]);
    #pragma unroll
    for (int h = 0; h < 2; ++h)
        #pragma unroll
        for (int c = 0; c < 2; ++c) pin8(whf[h][c]);
    #pragma unroll
    for (int t = 0; t < 4; ++t) { pin4(b0q[t]); pin4(b1q[t]); }
    pin4(brq); pin4(sIn);

    // ---------- main loop: 16 rows per wave-tile, persistent stride ----------
    int tile = blockIdx.x * WPB + wid;
    if (tile >= num_tiles) return;

    // prefetch first A-raw fp32: two dwordx4 per lane, coalesced 2 KiB/tile
    const float* fp = feat + (size_t)(tile*16 + n)*32 + 8*q;
    f32x4 aLo = __builtin_nontemporal_load((const f32x4*)fp);
    f32x4 aHi = __builtin_nontemporal_load((const f32x4*)fp + 1);

    while (true) {
        const int  nxt  = tile + wave_stride;
        const bool more = (nxt < num_tiles);
        const int  pf   = more ? nxt : tile;
        const float* fpn = feat + (size_t)(pf*16 + n)*32 + 8*q;
        f32x4 aLoN = __builtin_nontemporal_load((const f32x4*)fpn);
        f32x4 aHiN = __builtin_nontemporal_load((const f32x4*)fpn + 1);

        const int rowbase = tile * 16;
        bf16x8 a0 = cvt8(aLo, aHi);      // B'-frag: lane(n,q) = feat[n][8q+j]

        // ---- layer 0 (swapped): x0^T = relu(W0^T feat^T + b0) ----
        f32x4 acc0[4];
        #pragma unroll
        for (int t = 0; t < 4; ++t)
            acc0[t] = __builtin_amdgcn_mfma_f32_16x16x32_bf16(w0f[t], a0, b0q[t], 0, 0, 0);

        bf16x8 a1[2];
        relu_xpose(acc0, a1, addrA, addrB, hiq);

        // ---- layer 1 (swapped): x1^T = relu(W1^T x0^T + b1) ----
        f32x4 acc1[4];
        #pragma unroll
        for (int t = 0; t < 4; ++t) {
            acc1[t] = __builtin_amdgcn_mfma_f32_16x16x32_bf16(w1f[t][0], a1[0], b1q[t], 0, 0, 0);
            acc1[t] = __builtin_amdgcn_mfma_f32_16x16x32_bf16(w1f[t][1], a1[1], acc1[t], 0, 0, 0);
        }

        bf16x8 ah[2];
        relu_xpose(acc1, ah, addrA, addrB, hiq);

        // ---- heads: rgb^T = Wr^T x1^T + br ; s^T = Ws^T x1^T + (bs-1) ----
        f32x4 aR = __builtin_amdgcn_mfma_f32_16x16x32_bf16(whf[0][0], ah[0], brq, 0, 0, 0);
        aR       = __builtin_amdgcn_mfma_f32_16x16x32_bf16(whf[0][1], ah[1], aR,  0, 0, 0);
        f32x4 aS = __builtin_amdgcn_mfma_f32_16x16x32_bf16(whf[1][0], ah[0], sIn, 0, 0, 0);
        aS       = __builtin_amdgcn_mfma_f32_16x16x32_bf16(whf[1][1], ah[1], aS,  0, 0, 0);

        // ---- rgb: lane(n,q) holds rgb[n][4q..4q+3] -> direct coalesced dwordx4 ----
        __builtin_nontemporal_store(aR, (f32x4*)(out_rgb + ((size_t)rowbase + n) * 16 + 4*q));

        // ---- sigma: q==0 lanes hold sigma[n] in reg 0; softplus + 64B store ----
        if (q == 0) {
            float z = aS[0];
            float sp = fmaxf(z, 0.0f) + log1pf(expf(-fabsf(z)));
            __builtin_nontemporal_store(sp, out_sigma + rowbase + n);
        }

        if (!more) break;
        tile = nxt;
        aLo  = aLoN;
        aHi  = aHiN;
    }
}

extern "C" void kernel_launch(void* const* d_in, const int* in_sizes, int n_in,
                              void* d_out, int out_size, void* d_ws, size_t ws_size,
                              hipStream_t stream) {
    const float* feat = (const float*)d_in[0];
    const float* W0   = (const float*)d_in[1];
    const float* b0   = (const float*)d_in[2];
    const float* W1   = (const float*)d_in[3];
    const float* b1   = (const float*)d_in[4];
    const float* Ws   = (const float*)d_in[5];
    const float* bs   = (const float*)d_in[6];
    const float* Wr   = (const float*)d_in[7];
    const float* br   = (const float*)d_in[8];

    const int B         = in_sizes[0] / 32;      // 2,097,152
    const int num_tiles = B / 16;                // 131,072

    float* out_sigma = (float*)d_out;            // [B]
    float* out_rgb   = out_sigma + B;            // [B,16]

    // 3 blocks/CU resident (launch_bounds(256,3)) x 256 CUs -> fully persistent
    const int blocks = 768;
    ngp_mlp_kernel<<<blocks, 256, 0, stream>>>(feat, W0, b0, W1, b1, Ws, bs, Wr, br,
                                               out_sigma, out_rgb,
                                               num_tiles, blocks * WPB);
}

// Round 3
// 419.323 us; speedup vs baseline: 1.0465x; 1.0465x over previous
//
#include <hip/hip_runtime.h>
#include <hip/hip_bf16.h>
#include <math.h>

typedef __bf16 bf16_t;
typedef __bf16 bf16x8 __attribute__((ext_vector_type(8)));
typedef float  f32x4  __attribute__((ext_vector_type(4)));

#define WPB 4    // waves per block

// MFMA 16x16x32 layouts (m89/m120-verified):
//   A: lane(m = lane&15, q = lane>>4) holds A[m][8q+j], j=0..7
//   B: lane(n = lane&15, q)           holds B[8q+j][n]
//   C: lane(n = lane&15, q) reg r     holds C[4q+r][n]
//
// r4: operand-SWAPPED MFMA (y^T = W^T x^T) -> C is row-per-lane,
//     rgb store direct-coalesced, bias rides in as MFMA C operand.
//
// r6: K-PERMUTATION INVARIANCE — delete the cross-lane transpose.
// The contraction sum_k x[k]*W[k][.] is invariant under relabeling k, and we
// build the weight frags ourselves. Redefine the contraction-slot->channel map
//     ch(q,c,j) = 16*(2c + (j>>2)) + 4q + (j&3)
// (per q-group & chunk a bijection onto 32 channels). Then the next layer's
// B-frag chunk c is EXACTLY cvt8(acc[2c], acc[2c+1]) — pure in-lane ReLU+pack,
// zero ds_bpermute, zero cndmask. W1/Wr/Ws row gathers use ch() at init.
// Layer-0 input, rgb/sigma output layouts unchanged (canonical channel order).
//
// r5 (kept): non-temporal hints on read-once feat / write-once rgb+sigma.
// r3 (kept): pin() stops LLVM rematerializing invariant weight loads in-loop.

__device__ __forceinline__ void pin8(bf16x8& x) {
    f32x4 t = __builtin_bit_cast(f32x4, x);
    asm volatile("" : "+v"(t));
    x = __builtin_bit_cast(bf16x8, t);
}
__device__ __forceinline__ void pin4(f32x4& x) { asm volatile("" : "+v"(x)); }

__device__ __forceinline__ bf16x8 cvt8(f32x4 lo, f32x4 hi) {
    bf16x8 r;
    #pragma unroll
    for (int j = 0; j < 4; ++j) { r[j] = (bf16_t)lo[j]; r[4 + j] = (bf16_t)hi[j]; }
    return r;
}

// ReLU + bf16 pair-pack (v_cvt_pk_bf16_f32): acc pair -> next-layer B-frag chunk.
__device__ __forceinline__ bf16x8 relu_pack(const f32x4 a, const f32x4 b) {
    bf16x8 r;
    #pragma unroll
    for (int j = 0; j < 4; ++j) {
        r[j]     = (bf16_t)fmaxf(a[j], 0.0f);
        r[4 + j] = (bf16_t)fmaxf(b[j], 0.0f);
    }
    return r;
}

__global__ __launch_bounds__(256, 3)   // zero LDS, ~160 live VGPR -> 12 waves/CU
void ngp_mlp_kernel(const float* __restrict__ feat,
                    const float* __restrict__ W0,
                    const float* __restrict__ b0,
                    const float* __restrict__ W1,
                    const float* __restrict__ b1,
                    const float* __restrict__ Ws,
                    const float* __restrict__ bs,
                    const float* __restrict__ Wr,
                    const float* __restrict__ br,
                    float* __restrict__ out_sigma,
                    float* __restrict__ out_rgb,
                    int num_tiles, int wave_stride)
{
    const int tid  = threadIdx.x;
    const int wid  = tid >> 6;
    const int lane = tid & 63;
    const int n    = lane & 15;
    const int q    = lane >> 4;

    // ---------- one-time weight fragment construction (L2/L3-resident) ----------
    bf16x8 w0f[4];                       // W0 [32 x 64]: canonical gather (layer-0
    #pragma unroll                       // input is canonical feat layout)
    for (int t = 0; t < 4; ++t)
        #pragma unroll
        for (int j = 0; j < 8; ++j)
            w0f[t][j] = (bf16_t)W0[(8*q + j)*64 + 16*t + n];

    // permuted row gathers: contraction slot (q,c,j) carries channel ch(q,c,j)
    bf16x8 w1f[4][2];                    // W1 [64 x 64]: tile t, K-chunk c
    #pragma unroll
    for (int t = 0; t < 4; ++t)
        #pragma unroll
        for (int c = 0; c < 2; ++c)
            #pragma unroll
            for (int j = 0; j < 8; ++j) {
                const int ch = 16*(2*c + (j >> 2)) + 4*q + (j & 3);
                w1f[t][c][j] = (bf16_t)W1[ch*64 + 16*t + n];
            }

    bf16x8 whf[2][2];                    // heads: tile0 = Wr^T rows, tile1 row0 = Ws^T
    #pragma unroll
    for (int c = 0; c < 2; ++c)
        #pragma unroll
        for (int j = 0; j < 8; ++j) {
            const int ch = 16*(2*c + (j >> 2)) + 4*q + (j & 3);
            whf[0][c][j] = (bf16_t)Wr[ch*16 + n];
            whf[1][c][j] = (n == 0) ? (bf16_t)Ws[ch] : (bf16_t)0.0f;
        }

    // per-output-channel biases: channel = 16t + 4q + r  -> f32x4 per tile
    f32x4 b0q[4], b1q[4];
    #pragma unroll
    for (int t = 0; t < 4; ++t) {
        b0q[t] = *(const f32x4*)(b0 + 16*t + 4*q);
        b1q[t] = *(const f32x4*)(b1 + 16*t + 4*q);
    }
    f32x4 brq = *(const f32x4*)(br + 4*q);
    f32x4 sIn = (f32x4){ (q == 0) ? (bs[0] - 1.0f) : 0.0f, 0.0f, 0.0f, 0.0f };

    // ---- pin everything: kill invariant-load rematerialization ----
    #pragma unroll
    for (int t = 0; t < 4; ++t) pin8(w0f[t]);
    #pragma unroll
    for (int t = 0; t < 4; ++t)
        #pragma unroll
        for (int c = 0; c < 2; ++c) pin8(w1f[t][c]);
    #pragma unroll
    for (int h = 0; h < 2; ++h)
        #pragma unroll
        for (int c = 0; c < 2; ++c) pin8(whf[h][c]);
    #pragma unroll
    for (int t = 0; t < 4; ++t) { pin4(b0q[t]); pin4(b1q[t]); }
    pin4(brq); pin4(sIn);

    // ---------- main loop: 16 rows per wave-tile, persistent stride ----------
    int tile = blockIdx.x * WPB + wid;
    if (tile >= num_tiles) return;

    // prefetch first A-raw fp32: two dwordx4 per lane, coalesced 2 KiB/tile
    const float* fp = feat + (size_t)(tile*16 + n)*32 + 8*q;
    f32x4 aLo = __builtin_nontemporal_load((const f32x4*)fp);
    f32x4 aHi = __builtin_nontemporal_load((const f32x4*)fp + 1);

    while (true) {
        const int  nxt  = tile + wave_stride;
        const bool more = (nxt < num_tiles);
        const int  pf   = more ? nxt : tile;
        const float* fpn = feat + (size_t)(pf*16 + n)*32 + 8*q;
        f32x4 aLoN = __builtin_nontemporal_load((const f32x4*)fpn);
        f32x4 aHiN = __builtin_nontemporal_load((const f32x4*)fpn + 1);

        const int rowbase = tile * 16;
        bf16x8 a0 = cvt8(aLo, aHi);      // B-frag: lane(n,q) = feat[n][8q+j]

        // ---- layer 0 (swapped): x0^T = relu(W0^T feat^T + b0) ----
        f32x4 acc0[4];
        #pragma unroll
        for (int t = 0; t < 4; ++t)
            acc0[t] = __builtin_amdgcn_mfma_f32_16x16x32_bf16(w0f[t], a0, b0q[t], 0, 0, 0);

        // next-layer B-frags: pure in-lane ReLU+pack (K-permuted weight gather)
        bf16x8 a1[2];
        a1[0] = relu_pack(acc0[0], acc0[1]);
        a1[1] = relu_pack(acc0[2], acc0[3]);

        // ---- layer 1 (swapped, permuted K): x1^T = relu(W1^T x0^T + b1) ----
        f32x4 acc1[4];
        #pragma unroll
        for (int t = 0; t < 4; ++t) {
            acc1[t] = __builtin_amdgcn_mfma_f32_16x16x32_bf16(w1f[t][0], a1[0], b1q[t], 0, 0, 0);
            acc1[t] = __builtin_amdgcn_mfma_f32_16x16x32_bf16(w1f[t][1], a1[1], acc1[t], 0, 0, 0);
        }

        bf16x8 ah[2];
        ah[0] = relu_pack(acc1[0], acc1[1]);
        ah[1] = relu_pack(acc1[2], acc1[3]);

        // ---- heads: rgb^T = Wr^T x1^T + br ; s^T = Ws^T x1^T + (bs-1) ----
        f32x4 aR = __builtin_amdgcn_mfma_f32_16x16x32_bf16(whf[0][0], ah[0], brq, 0, 0, 0);
        aR       = __builtin_amdgcn_mfma_f32_16x16x32_bf16(whf[0][1], ah[1], aR,  0, 0, 0);
        f32x4 aS = __builtin_amdgcn_mfma_f32_16x16x32_bf16(whf[1][0], ah[0], sIn, 0, 0, 0);
        aS       = __builtin_amdgcn_mfma_f32_16x16x32_bf16(whf[1][1], ah[1], aS,  0, 0, 0);

        // ---- rgb: lane(n,q) holds rgb[n][4q..4q+3] -> direct coalesced dwordx4 ----
        __builtin_nontemporal_store(aR, (f32x4*)(out_rgb + ((size_t)rowbase + n) * 16 + 4*q));

        // ---- sigma: q==0 lanes hold sigma[n] in reg 0; softplus + 64B store ----
        if (q == 0) {
            float z = aS[0];
            float sp = fmaxf(z, 0.0f) + log1pf(expf(-fabsf(z)));
            __builtin_nontemporal_store(sp, out_sigma + rowbase + n);
        }

        if (!more) break;
        tile = nxt;
        aLo  = aLoN;
        aHi  = aHiN;
    }
}

extern "C" void kernel_launch(void* const* d_in, const int* in_sizes, int n_in,
                              void* d_out, int out_size, void* d_ws, size_t ws_size,
                              hipStream_t stream) {
    const float* feat = (const float*)d_in[0];
    const float* W0   = (const float*)d_in[1];
    const float* b0   = (const float*)d_in[2];
    const float* W1   = (const float*)d_in[3];
    const float* b1   = (const float*)d_in[4];
    const float* Ws   = (const float*)d_in[5];
    const float* bs   = (const float*)d_in[6];
    const float* Wr   = (const float*)d_in[7];
    const float* br   = (const float*)d_in[8];

    const int B         = in_sizes[0] / 32;      // 2,097,152
    const int num_tiles = B / 16;                // 131,072

    float* out_sigma = (float*)d_out;            // [B]
    float* out_rgb   = out_sigma + B;            // [B,16]

    // 3 blocks/CU resident (launch_bounds(256,3)) x 256 CUs -> fully persistent
    const int blocks = 768;
    ngp_mlp_kernel<<<blocks, 256, 0, stream>>>(feat, W0, b0, W1, b1, Ws, bs, Wr, br,
                                               out_sigma, out_rgb,
                                               num_tiles, blocks * WPB);
}

// Round 4
// 407.135 us; speedup vs baseline: 1.0778x; 1.0299x over previous
//
#include <hip/hip_runtime.h>
#include <hip/hip_bf16.h>
#include <math.h>

typedef __bf16 bf16_t;
typedef __bf16 bf16x8 __attribute__((ext_vector_type(8)));
typedef float  f32x4  __attribute__((ext_vector_type(4)));

#define WPB 4    // waves per block

// MFMA 16x16x32 layouts (m89/m120-verified):
//   A: lane(m = lane&15, q = lane>>4) holds A[m][8q+j], j=0..7
//   B: lane(n = lane&15, q)           holds B[8q+j][n]
//   C: lane(n = lane&15, q) reg r     holds C[4q+r][n]
//
// r4: operand-SWAPPED MFMA (y^T = W^T x^T) -> C is row-per-lane,
//     rgb store direct-coalesced, bias rides in as MFMA C operand.
//
// r6: K-PERMUTATION INVARIANCE — contraction-slot->channel map
//     ch(q,c,j) = 16*(2c + (j>>2)) + 4q + (j&3)
// makes the next layer's B-frag chunk c EXACTLY relu_pack(acc[2c],acc[2c+1])
// — pure in-lane ReLU+pack, zero cross-lane traffic. W1/Wr/Ws gathers use ch().
//
// r7: REGISTER-PRESSURE RELIEF. r6's +20us from -20 regs => we were at the
// (256,3) 170-VGPR cliff and the allocator was spilling loop-carried state to
// scratch (serial ~300cy reloads per tile = the latency mystery). Now:
//   - __launch_bounds__(256,2): cap 256, zero spill by construction.
//   - spend the slack on DEPTH-2 feat prefetch (loads 2 iterations ahead,
//     ~2x compute of HBM-latency cover, 4KB/wave outstanding).
//   - branchless softplus via v_exp/v_log (no libm log1pf sequence).
//   - grid 512 blocks = exactly 2 resident/CU, 64 tiles/wave.
//
// r5 (kept): non-temporal hints on read-once feat / write-once rgb+sigma.
// r3 (kept): pin() stops LLVM rematerializing invariant weight loads in-loop.

__device__ __forceinline__ void pin8(bf16x8& x) {
    f32x4 t = __builtin_bit_cast(f32x4, x);
    asm volatile("" : "+v"(t));
    x = __builtin_bit_cast(bf16x8, t);
}
__device__ __forceinline__ void pin4(f32x4& x) { asm volatile("" : "+v"(x)); }

__device__ __forceinline__ bf16x8 cvt8(f32x4 lo, f32x4 hi) {
    bf16x8 r;
    #pragma unroll
    for (int j = 0; j < 4; ++j) { r[j] = (bf16_t)lo[j]; r[4 + j] = (bf16_t)hi[j]; }
    return r;
}

// ReLU + bf16 pair-pack (v_cvt_pk_bf16_f32): acc pair -> next-layer B-frag chunk.
__device__ __forceinline__ bf16x8 relu_pack(const f32x4 a, const f32x4 b) {
    bf16x8 r;
    #pragma unroll
    for (int j = 0; j < 4; ++j) {
        r[j]     = (bf16_t)fmaxf(a[j], 0.0f);
        r[4 + j] = (bf16_t)fmaxf(b[j], 0.0f);
    }
    return r;
}

__global__ __launch_bounds__(256, 2)   // cap 256 VGPR: zero spill; 8 waves/CU
void ngp_mlp_kernel(const float* __restrict__ feat,
                    const float* __restrict__ W0,
                    const float* __restrict__ b0,
                    const float* __restrict__ W1,
                    const float* __restrict__ b1,
                    const float* __restrict__ Ws,
                    const float* __restrict__ bs,
                    const float* __restrict__ Wr,
                    const float* __restrict__ br,
                    float* __restrict__ out_sigma,
                    float* __restrict__ out_rgb,
                    int num_tiles, int wave_stride)
{
    const int tid  = threadIdx.x;
    const int wid  = tid >> 6;
    const int lane = tid & 63;
    const int n    = lane & 15;
    const int q    = lane >> 4;

    // ---------- one-time weight fragment construction (L2/L3-resident) ----------
    bf16x8 w0f[4];                       // W0 [32 x 64]: canonical gather (layer-0
    #pragma unroll                       // input is canonical feat layout)
    for (int t = 0; t < 4; ++t)
        #pragma unroll
        for (int j = 0; j < 8; ++j)
            w0f[t][j] = (bf16_t)W0[(8*q + j)*64 + 16*t + n];

    // permuted row gathers: contraction slot (q,c,j) carries channel ch(q,c,j)
    bf16x8 w1f[4][2];                    // W1 [64 x 64]: tile t, K-chunk c
    #pragma unroll
    for (int t = 0; t < 4; ++t)
        #pragma unroll
        for (int c = 0; c < 2; ++c)
            #pragma unroll
            for (int j = 0; j < 8; ++j) {
                const int ch = 16*(2*c + (j >> 2)) + 4*q + (j & 3);
                w1f[t][c][j] = (bf16_t)W1[ch*64 + 16*t + n];
            }

    bf16x8 whf[2][2];                    // heads: tile0 = Wr^T rows, tile1 row0 = Ws^T
    #pragma unroll
    for (int c = 0; c < 2; ++c)
        #pragma unroll
        for (int j = 0; j < 8; ++j) {
            const int ch = 16*(2*c + (j >> 2)) + 4*q + (j & 3);
            whf[0][c][j] = (bf16_t)Wr[ch*16 + n];
            whf[1][c][j] = (n == 0) ? (bf16_t)Ws[ch] : (bf16_t)0.0f;
        }

    // per-output-channel biases: channel = 16t + 4q + r  -> f32x4 per tile
    f32x4 b0q[4], b1q[4];
    #pragma unroll
    for (int t = 0; t < 4; ++t) {
        b0q[t] = *(const f32x4*)(b0 + 16*t + 4*q);
        b1q[t] = *(const f32x4*)(b1 + 16*t + 4*q);
    }
    f32x4 brq = *(const f32x4*)(br + 4*q);
    f32x4 sIn = (f32x4){ (q == 0) ? (bs[0] - 1.0f) : 0.0f, 0.0f, 0.0f, 0.0f };

    // ---- pin everything: kill invariant-load rematerialization ----
    #pragma unroll
    for (int t = 0; t < 4; ++t) pin8(w0f[t]);
    #pragma unroll
    for (int t = 0; t < 4; ++t)
        #pragma unroll
        for (int c = 0; c < 2; ++c) pin8(w1f[t][c]);
    #pragma unroll
    for (int h = 0; h < 2; ++h)
        #pragma unroll
        for (int c = 0; c < 2; ++c) pin8(whf[h][c]);
    #pragma unroll
    for (int t = 0; t < 4; ++t) { pin4(b0q[t]); pin4(b1q[t]); }
    pin4(brq); pin4(sIn);

    // ---------- main loop: 16 rows per wave-tile, persistent stride ----------
    int tile = blockIdx.x * WPB + wid;
    if (tile >= num_tiles) return;

    const int S = wave_stride;

    // depth-2 prefetch pipeline: cur = tile, n1 = tile+S
    const float* fp0 = feat + (size_t)(tile*16 + n)*32 + 8*q;
    f32x4 curLo = __builtin_nontemporal_load((const f32x4*)fp0);
    f32x4 curHi = __builtin_nontemporal_load((const f32x4*)fp0 + 1);

    const int t1 = (tile + S < num_tiles) ? tile + S : tile;
    const float* fp1 = feat + (size_t)(t1*16 + n)*32 + 8*q;
    f32x4 n1Lo = __builtin_nontemporal_load((const f32x4*)fp1);
    f32x4 n1Hi = __builtin_nontemporal_load((const f32x4*)fp1 + 1);

    while (true) {
        // issue prefetch for tile+2S (clamped) — 2 iterations of latency cover
        const int  nxt2 = tile + 2*S;
        const int  pf   = (nxt2 < num_tiles) ? nxt2 : tile;
        const float* fpn = feat + (size_t)(pf*16 + n)*32 + 8*q;
        f32x4 n2Lo = __builtin_nontemporal_load((const f32x4*)fpn);
        f32x4 n2Hi = __builtin_nontemporal_load((const f32x4*)fpn + 1);

        const int rowbase = tile * 16;
        bf16x8 a0 = cvt8(curLo, curHi);  // B-frag: lane(n,q) = feat[n][8q+j]

        // ---- layer 0 (swapped): x0^T = relu(W0^T feat^T + b0) ----
        f32x4 acc0[4];
        #pragma unroll
        for (int t = 0; t < 4; ++t)
            acc0[t] = __builtin_amdgcn_mfma_f32_16x16x32_bf16(w0f[t], a0, b0q[t], 0, 0, 0);

        // next-layer B-frags: pure in-lane ReLU+pack (K-permuted weight gather)
        bf16x8 a1[2];
        a1[0] = relu_pack(acc0[0], acc0[1]);
        a1[1] = relu_pack(acc0[2], acc0[3]);

        // ---- layer 1 (swapped, permuted K): x1^T = relu(W1^T x0^T + b1) ----
        f32x4 acc1[4];
        #pragma unroll
        for (int t = 0; t < 4; ++t) {
            acc1[t] = __builtin_amdgcn_mfma_f32_16x16x32_bf16(w1f[t][0], a1[0], b1q[t], 0, 0, 0);
            acc1[t] = __builtin_amdgcn_mfma_f32_16x16x32_bf16(w1f[t][1], a1[1], acc1[t], 0, 0, 0);
        }

        bf16x8 ah[2];
        ah[0] = relu_pack(acc1[0], acc1[1]);
        ah[1] = relu_pack(acc1[2], acc1[3]);

        // ---- heads: rgb^T = Wr^T x1^T + br ; s^T = Ws^T x1^T + (bs-1) ----
        f32x4 aR = __builtin_amdgcn_mfma_f32_16x16x32_bf16(whf[0][0], ah[0], brq, 0, 0, 0);
        aR       = __builtin_amdgcn_mfma_f32_16x16x32_bf16(whf[0][1], ah[1], aR,  0, 0, 0);
        f32x4 aS = __builtin_amdgcn_mfma_f32_16x16x32_bf16(whf[1][0], ah[0], sIn, 0, 0, 0);
        aS       = __builtin_amdgcn_mfma_f32_16x16x32_bf16(whf[1][1], ah[1], aS,  0, 0, 0);

        // ---- rgb: lane(n,q) holds rgb[n][4q..4q+3] -> direct coalesced dwordx4 ----
        __builtin_nontemporal_store(aR, (f32x4*)(out_rgb + ((size_t)rowbase + n) * 16 + 4*q));

        // ---- sigma: q==0 lanes hold sigma[n] in reg 0; branchless fast softplus ----
        if (q == 0) {
            float z  = aS[0];
            float e  = __builtin_exp2f(-fabsf(z) * 1.44269504f);     // e^{-|z|}
            float sp = fmaxf(z, 0.0f) + __builtin_log2f(1.0f + e) * 0.69314718f;
            __builtin_nontemporal_store(sp, out_sigma + rowbase + n);
        }

        if (tile + S >= num_tiles) break;
        tile  = tile + S;
        curLo = n1Lo;  curHi = n1Hi;
        n1Lo  = n2Lo;  n1Hi  = n2Hi;
    }
}

extern "C" void kernel_launch(void* const* d_in, const int* in_sizes, int n_in,
                              void* d_out, int out_size, void* d_ws, size_t ws_size,
                              hipStream_t stream) {
    const float* feat = (const float*)d_in[0];
    const float* W0   = (const float*)d_in[1];
    const float* b0   = (const float*)d_in[2];
    const float* W1   = (const float*)d_in[3];
    const float* b1   = (const float*)d_in[4];
    const float* Ws   = (const float*)d_in[5];
    const float* bs   = (const float*)d_in[6];
    const float* Wr   = (const float*)d_in[7];
    const float* br   = (const float*)d_in[8];

    const int B         = in_sizes[0] / 32;      // 2,097,152
    const int num_tiles = B / 16;                // 131,072

    float* out_sigma = (float*)d_out;            // [B]
    float* out_rgb   = out_sigma + B;            // [B,16]

    // 2 blocks/CU resident (launch_bounds(256,2)) x 256 CUs -> fully persistent,
    // 2048 waves, exactly 64 tiles per wave
    const int blocks = 512;
    ngp_mlp_kernel<<<blocks, 256, 0, stream>>>(feat, W0, b0, W1, b1, Ws, bs, Wr, br,
                                               out_sigma, out_rgb,
                                               num_tiles, blocks * WPB);
}

// Round 5
// 405.054 us; speedup vs baseline: 1.0833x; 1.0051x over previous
//
#include <hip/hip_runtime.h>
#include <hip/hip_bf16.h>
#include <math.h>

typedef __bf16 bf16_t;
typedef __bf16 bf16x8 __attribute__((ext_vector_type(8)));
typedef float  f32x4  __attribute__((ext_vector_type(4)));

#define WPB 4    // waves per block

// MFMA 16x16x32 layouts (m89/m120-verified):
//   A: lane(m = lane&15, q = lane>>4) holds A[m][8q+j], j=0..7
//   B: lane(n = lane&15, q)           holds B[8q+j][n]
//   C: lane(n = lane&15, q) reg r     holds C[4q+r][n]
//
// r4: operand-SWAPPED MFMA (y^T = W^T x^T) -> C row-per-lane, coalesced rgb
//     store, bias rides in as the MFMA C operand.
// r6: K-PERMUTATION INVARIANCE — ch(q,c,j) = 16*(2c+(j>>2)) + 4q + (j&3)
//     makes the next layer's B-frag = relu_pack(acc[2c],acc[2c+1]) in-lane.
// r7: (256,2) spill relief + depth-2 prefetch (kernel ~95 -> ~83us).
//
// r8: DUAL-TILE ILP. At 2 waves/SIMD the per-tile serial MFMA chain
// (L0 -> pack -> L1 -> pack -> heads, ~700-900cy of latency) is uncoverable:
// per-SIMD issue demand is ~200cy/tile but observed is ~1556cy/tile. Process
// TWO ADJACENT tiles per iteration with independent chains — tile B's layer-0
// issues under tile A's layer-1 latency. Also makes feat fetch 4KiB and rgb
// store 2KiB contiguous per wave. ~210 VGPR peak, still under the 256 cap.
//
// r5 (kept): non-temporal hints on read-once feat / write-once rgb+sigma.
// r3 (kept): pin() stops LLVM rematerializing invariant weight loads in-loop.

__device__ __forceinline__ void pin8(bf16x8& x) {
    f32x4 t = __builtin_bit_cast(f32x4, x);
    asm volatile("" : "+v"(t));
    x = __builtin_bit_cast(bf16x8, t);
}
__device__ __forceinline__ void pin4(f32x4& x) { asm volatile("" : "+v"(x)); }

__device__ __forceinline__ bf16x8 cvt8(f32x4 lo, f32x4 hi) {
    bf16x8 r;
    #pragma unroll
    for (int j = 0; j < 4; ++j) { r[j] = (bf16_t)lo[j]; r[4 + j] = (bf16_t)hi[j]; }
    return r;
}

// ReLU + bf16 pair-pack (v_cvt_pk_bf16_f32): acc pair -> next-layer B-frag chunk.
__device__ __forceinline__ bf16x8 relu_pack(const f32x4 a, const f32x4 b) {
    bf16x8 r;
    #pragma unroll
    for (int j = 0; j < 4; ++j) {
        r[j]     = (bf16_t)fmaxf(a[j], 0.0f);
        r[4 + j] = (bf16_t)fmaxf(b[j], 0.0f);
    }
    return r;
}

__global__ __launch_bounds__(256, 2)   // cap 256 VGPR: zero spill; 8 waves/CU
void ngp_mlp_kernel(const float* __restrict__ feat,
                    const float* __restrict__ W0,
                    const float* __restrict__ b0,
                    const float* __restrict__ W1,
                    const float* __restrict__ b1,
                    const float* __restrict__ Ws,
                    const float* __restrict__ bs,
                    const float* __restrict__ Wr,
                    const float* __restrict__ br,
                    float* __restrict__ out_sigma,
                    float* __restrict__ out_rgb,
                    int num_pairs, int wave_stride)
{
    const int tid  = threadIdx.x;
    const int wid  = tid >> 6;
    const int lane = tid & 63;
    const int n    = lane & 15;
    const int q    = lane >> 4;

    // ---------- one-time weight fragment construction (L2/L3-resident) ----------
    bf16x8 w0f[4];                       // W0 [32 x 64]: canonical gather
    #pragma unroll
    for (int t = 0; t < 4; ++t)
        #pragma unroll
        for (int j = 0; j < 8; ++j)
            w0f[t][j] = (bf16_t)W0[(8*q + j)*64 + 16*t + n];

    // permuted row gathers: contraction slot (q,c,j) carries channel ch(q,c,j)
    bf16x8 w1f[4][2];                    // W1 [64 x 64]: tile t, K-chunk c
    #pragma unroll
    for (int t = 0; t < 4; ++t)
        #pragma unroll
        for (int c = 0; c < 2; ++c)
            #pragma unroll
            for (int j = 0; j < 8; ++j) {
                const int ch = 16*(2*c + (j >> 2)) + 4*q + (j & 3);
                w1f[t][c][j] = (bf16_t)W1[ch*64 + 16*t + n];
            }

    bf16x8 whf[2][2];                    // heads: tile0 = Wr^T rows, tile1 row0 = Ws^T
    #pragma unroll
    for (int c = 0; c < 2; ++c)
        #pragma unroll
        for (int j = 0; j < 8; ++j) {
            const int ch = 16*(2*c + (j >> 2)) + 4*q + (j & 3);
            whf[0][c][j] = (bf16_t)Wr[ch*16 + n];
            whf[1][c][j] = (n == 0) ? (bf16_t)Ws[ch] : (bf16_t)0.0f;
        }

    // per-output-channel biases: channel = 16t + 4q + r  -> f32x4 per tile
    f32x4 b0q[4], b1q[4];
    #pragma unroll
    for (int t = 0; t < 4; ++t) {
        b0q[t] = *(const f32x4*)(b0 + 16*t + 4*q);
        b1q[t] = *(const f32x4*)(b1 + 16*t + 4*q);
    }
    f32x4 brq = *(const f32x4*)(br + 4*q);
    f32x4 sIn = (f32x4){ (q == 0) ? (bs[0] - 1.0f) : 0.0f, 0.0f, 0.0f, 0.0f };

    // ---- pin everything: kill invariant-load rematerialization ----
    #pragma unroll
    for (int t = 0; t < 4; ++t) pin8(w0f[t]);
    #pragma unroll
    for (int t = 0; t < 4; ++t)
        #pragma unroll
        for (int c = 0; c < 2; ++c) pin8(w1f[t][c]);
    #pragma unroll
    for (int h = 0; h < 2; ++h)
        #pragma unroll
        for (int c = 0; c < 2; ++c) pin8(whf[h][c]);
    #pragma unroll
    for (int t = 0; t < 4; ++t) { pin4(b0q[t]); pin4(b1q[t]); }
    pin4(brq); pin4(sIn);

    // ---------- main loop: one PAIR of adjacent tiles (32 rows) per iteration ----------
    int p = blockIdx.x * WPB + wid;      // pair index; tiles 2p, 2p+1
    if (p >= num_pairs) return;
    const int W = wave_stride;

    // feat addr for pair pp, tile half h: rows 32*pp + 16*h + n, cols 8q..
    // depth-2 prefetch pipeline over pairs: cur = p, n1 = p+W
    const float* fpc = feat + ((size_t)p*32 + n)*32 + 8*q;
    f32x4 cAlo = __builtin_nontemporal_load((const f32x4*)fpc);
    f32x4 cAhi = __builtin_nontemporal_load((const f32x4*)fpc + 1);
    f32x4 cBlo = __builtin_nontemporal_load((const f32x4*)(fpc + 512));
    f32x4 cBhi = __builtin_nontemporal_load((const f32x4*)(fpc + 512) + 1);

    const int p1 = (p + W < num_pairs) ? p + W : p;
    const float* fp1 = feat + ((size_t)p1*32 + n)*32 + 8*q;
    f32x4 nAlo = __builtin_nontemporal_load((const f32x4*)fp1);
    f32x4 nAhi = __builtin_nontemporal_load((const f32x4*)fp1 + 1);
    f32x4 nBlo = __builtin_nontemporal_load((const f32x4*)(fp1 + 512));
    f32x4 nBhi = __builtin_nontemporal_load((const f32x4*)(fp1 + 512) + 1);

    while (true) {
        // issue prefetch for pair p+2W (clamped) — 2 iterations of latency cover
        const int  p2 = p + 2*W;
        const int  pf = (p2 < num_pairs) ? p2 : p;
        const float* fpn = feat + ((size_t)pf*32 + n)*32 + 8*q;
        f32x4 mAlo = __builtin_nontemporal_load((const f32x4*)fpn);
        f32x4 mAhi = __builtin_nontemporal_load((const f32x4*)fpn + 1);
        f32x4 mBlo = __builtin_nontemporal_load((const f32x4*)(fpn + 512));
        f32x4 mBhi = __builtin_nontemporal_load((const f32x4*)(fpn + 512) + 1);

        const int rowA = p * 32;          // tile 2p   -> rows rowA..rowA+15
        const int rowB = rowA + 16;       // tile 2p+1 -> rows rowB..rowB+15
        bf16x8 a0A = cvt8(cAlo, cAhi);
        bf16x8 a0B = cvt8(cBlo, cBhi);

        // ---- layer 0 (swapped), both tiles interleaved ----
        f32x4 acc0A[4], acc0B[4];
        #pragma unroll
        for (int t = 0; t < 4; ++t) {
            acc0A[t] = __builtin_amdgcn_mfma_f32_16x16x32_bf16(w0f[t], a0A, b0q[t], 0, 0, 0);
            acc0B[t] = __builtin_amdgcn_mfma_f32_16x16x32_bf16(w0f[t], a0B, b0q[t], 0, 0, 0);
        }

        bf16x8 a1A[2], a1B[2];
        a1A[0] = relu_pack(acc0A[0], acc0A[1]);
        a1B[0] = relu_pack(acc0B[0], acc0B[1]);
        a1A[1] = relu_pack(acc0A[2], acc0A[3]);
        a1B[1] = relu_pack(acc0B[2], acc0B[3]);

        // ---- layer 1 (swapped, permuted K), both tiles interleaved ----
        f32x4 acc1A[4], acc1B[4];
        #pragma unroll
        for (int t = 0; t < 4; ++t) {
            acc1A[t] = __builtin_amdgcn_mfma_f32_16x16x32_bf16(w1f[t][0], a1A[0], b1q[t], 0, 0, 0);
            acc1B[t] = __builtin_amdgcn_mfma_f32_16x16x32_bf16(w1f[t][0], a1B[0], b1q[t], 0, 0, 0);
            acc1A[t] = __builtin_amdgcn_mfma_f32_16x16x32_bf16(w1f[t][1], a1A[1], acc1A[t], 0, 0, 0);
            acc1B[t] = __builtin_amdgcn_mfma_f32_16x16x32_bf16(w1f[t][1], a1B[1], acc1B[t], 0, 0, 0);
        }

        bf16x8 ahA[2], ahB[2];
        ahA[0] = relu_pack(acc1A[0], acc1A[1]);
        ahB[0] = relu_pack(acc1B[0], acc1B[1]);
        ahA[1] = relu_pack(acc1A[2], acc1A[3]);
        ahB[1] = relu_pack(acc1B[2], acc1B[3]);

        // ---- heads, both tiles interleaved ----
        f32x4 aRA = __builtin_amdgcn_mfma_f32_16x16x32_bf16(whf[0][0], ahA[0], brq, 0, 0, 0);
        f32x4 aRB = __builtin_amdgcn_mfma_f32_16x16x32_bf16(whf[0][0], ahB[0], brq, 0, 0, 0);
        aRA       = __builtin_amdgcn_mfma_f32_16x16x32_bf16(whf[0][1], ahA[1], aRA, 0, 0, 0);
        aRB       = __builtin_amdgcn_mfma_f32_16x16x32_bf16(whf[0][1], ahB[1], aRB, 0, 0, 0);
        f32x4 aSA = __builtin_amdgcn_mfma_f32_16x16x32_bf16(whf[1][0], ahA[0], sIn, 0, 0, 0);
        f32x4 aSB = __builtin_amdgcn_mfma_f32_16x16x32_bf16(whf[1][0], ahB[0], sIn, 0, 0, 0);
        aSA       = __builtin_amdgcn_mfma_f32_16x16x32_bf16(whf[1][1], ahA[1], aSA, 0, 0, 0);
        aSB       = __builtin_amdgcn_mfma_f32_16x16x32_bf16(whf[1][1], ahB[1], aSB, 0, 0, 0);

        // ---- rgb: lane(n,q) holds rgb[n][4q..4q+3] -> coalesced dwordx4 x2 ----
        __builtin_nontemporal_store(aRA, (f32x4*)(out_rgb + ((size_t)rowA + n) * 16 + 4*q));
        __builtin_nontemporal_store(aRB, (f32x4*)(out_rgb + ((size_t)rowB + n) * 16 + 4*q));

        // ---- sigma: q==0 lanes hold sigma[n] in reg 0; branchless fast softplus ----
        if (q == 0) {
            float zA  = aSA[0];
            float eA  = __builtin_exp2f(-fabsf(zA) * 1.44269504f);
            float spA = fmaxf(zA, 0.0f) + __builtin_log2f(1.0f + eA) * 0.69314718f;
            __builtin_nontemporal_store(spA, out_sigma + rowA + n);
            float zB  = aSB[0];
            float eB  = __builtin_exp2f(-fabsf(zB) * 1.44269504f);
            float spB = fmaxf(zB, 0.0f) + __builtin_log2f(1.0f + eB) * 0.69314718f;
            __builtin_nontemporal_store(spB, out_sigma + rowB + n);
        }

        if (p + W >= num_pairs) break;
        p += W;
        cAlo = nAlo; cAhi = nAhi; cBlo = nBlo; cBhi = nBhi;
        nAlo = mAlo; nAhi = mAhi; nBlo = mBlo; nBhi = mBhi;
    }
}

extern "C" void kernel_launch(void* const* d_in, const int* in_sizes, int n_in,
                              void* d_out, int out_size, void* d_ws, size_t ws_size,
                              hipStream_t stream) {
    const float* feat = (const float*)d_in[0];
    const float* W0   = (const float*)d_in[1];
    const float* b0   = (const float*)d_in[2];
    const float* W1   = (const float*)d_in[3];
    const float* b1   = (const float*)d_in[4];
    const float* Ws   = (const float*)d_in[5];
    const float* bs   = (const float*)d_in[6];
    const float* Wr   = (const float*)d_in[7];
    const float* br   = (const float*)d_in[8];

    const int B         = in_sizes[0] / 32;      // 2,097,152
    const int num_pairs = B / 32;                // 65,536 tile-pairs (32 rows each)

    float* out_sigma = (float*)d_out;            // [B]
    float* out_rgb   = out_sigma + B;            // [B,16]

    // 2 blocks/CU resident (launch_bounds(256,2)) x 256 CUs, 2048 waves
    // -> exactly 32 pairs per wave
    const int blocks = 512;
    ngp_mlp_kernel<<<blocks, 256, 0, stream>>>(feat, W0, b0, W1, b1, Ws, bs, Wr, br,
                                               out_sigma, out_rgb,
                                               num_pairs, blocks * WPB);
}